// Round 3
// baseline (236.830 us; speedup 1.0000x reference)
//
#include <hip/hip_runtime.h>
#include <hip/hip_bf16.h>
#include <math.h>

#define B_      2
#define L_      2048
#define DIM_    512
#define DINNER  1024
#define DTRANK  32
#define DSTATE  16
#define DCONV   4
#define BL      (B_ * L_)        // 4096
#define NCHUNK  64
#define CLEN    (L_ / NCHUNK)    // 32

typedef __attribute__((ext_vector_type(8))) short bf16x8;
typedef __attribute__((ext_vector_type(4))) float f32x4;

static __device__ __forceinline__ unsigned short f2bf(float f) {
  __hip_bfloat16 h = __float2bfloat16(f);
  return *(unsigned short*)&h;
}
static __device__ __forceinline__ float bf2f(unsigned short u) {
  return __uint_as_float(((unsigned int)u) << 16);
}

// async global->LDS, 16B per lane. LDS dest must be the WAVE-UNIFORM base;
// HW writes lane l at base + l*16 (linear, no scatter).
static __device__ __forceinline__ void gload16(const void* g, void* l) {
  __builtin_amdgcn_global_load_lds(
      (const __attribute__((address_space(1))) void*)g,
      (__attribute__((address_space(3))) void*)l, 16, 0, 0);
}

// softplus via HW exp/log
static __device__ __forceinline__ float softplus_f(float acc) {
  return (acc > 20.f) ? acc : __logf(1.f + __expf(acc));
}

// ------- merged: weight fp32->bf16 conversion + LayerNorm ------------------
__global__ __launch_bounds__(256) void cvt_ln_kernel(
    const float* __restrict__ s0, const float* __restrict__ s1,
    const float* __restrict__ s2, __hip_bfloat16* __restrict__ d0,
    __hip_bfloat16* __restrict__ d1, __hip_bfloat16* __restrict__ d2,
    const float* __restrict__ x, const float* __restrict__ g,
    const float* __restrict__ b, __hip_bfloat16* __restrict__ h) {
  int blk = blockIdx.x;
  if (blk < 1600) {
    int i = (blk * 256 + threadIdx.x) * 4;
    const float* s; __hip_bfloat16* d; int off;
    if (i < 1048576)            { s = s0; d = d0; off = i; }
    else if (i < 1048576+65536) { s = s1; d = d1; off = i - 1048576; }
    else                        { s = s2; d = d2; off = i - 1114112; }
    float4 v = *(const float4*)(s + off);
    d[off + 0] = __float2bfloat16(v.x);
    d[off + 1] = __float2bfloat16(v.y);
    d[off + 2] = __float2bfloat16(v.z);
    d[off + 3] = __float2bfloat16(v.w);
    return;
  }
  int row = (blk - 1600) * 4 + (threadIdx.x >> 6);
  int lane = threadIdx.x & 63;
  const float* xr = x + (size_t)row * DIM_;
  float v[8];
  float sum = 0.f;
#pragma unroll
  for (int i = 0; i < 8; i++) { v[i] = xr[lane + i * 64]; sum += v[i]; }
#pragma unroll
  for (int o = 32; o > 0; o >>= 1) sum += __shfl_xor(sum, o, 64);
  float mu = sum * (1.f / DIM_);
  float vs = 0.f;
#pragma unroll
  for (int i = 0; i < 8; i++) { float dd = v[i] - mu; vs += dd * dd; }
#pragma unroll
  for (int o = 32; o > 0; o >>= 1) vs += __shfl_xor(vs, o, 64);
  float rstd = rsqrtf(vs * (1.f / DIM_) + 1e-5f);
  __hip_bfloat16* hr = h + (size_t)row * DIM_;
#pragma unroll
  for (int i = 0; i < 8; i++) {
    int c = lane + i * 64;
    hr[c] = __float2bfloat16((v[i] - mu) * rstd * g[c] + b[c]);
  }
}

// ---------------- bf16 MFMA GEMM, 128x128 tile: C = A[M,K] * B[N,K]^T ------
template <bool ADD_RES, bool OUT_BF16>
__global__ __launch_bounds__(256) void gemm_mfma_128(
    const __hip_bfloat16* __restrict__ A, int lda,
    const __hip_bfloat16* __restrict__ Bw, int ldb,
    const float* __restrict__ Res, int ldr,
    void* __restrict__ C, int ldc, int K) {
  __shared__ short As[128 * 64];
  __shared__ short Bs[128 * 64];
  int t = threadIdx.x;
  int n0 = blockIdx.x * 128, m0 = blockIdx.y * 128;
  int w = t >> 6, lane = t & 63;
  int wm = (w >> 1) * 64, wn = (w & 1) * 64;
  int l15 = lane & 15, quad = lane >> 4;
  int lr = lane >> 3, lc = (lane & 7) * 8;
  const short* Ag = (const short*)A + (size_t)(m0 + w * 32 + lr) * lda + lc;
  const short* Bg = (const short*)Bw + (size_t)(n0 + w * 32 + lr) * ldb + lc;
  f32x4 acc[4][4];
#pragma unroll
  for (int i = 0; i < 4; i++)
#pragma unroll
    for (int j = 0; j < 4; j++) acc[i][j] = (f32x4){0.f, 0.f, 0.f, 0.f};
  for (int k0 = 0; k0 < K; k0 += 64) {
    __syncthreads();
#pragma unroll
    for (int p = 0; p < 4; p++) {
      gload16(Ag + (size_t)(p * 8) * lda + k0, &As[(w * 32 + p * 8) * 64]);
      gload16(Bg + (size_t)(p * 8) * ldb + k0, &Bs[(w * 32 + p * 8) * 64]);
    }
    __syncthreads();
#pragma unroll
    for (int kk = 0; kk < 64; kk += 32) {
      bf16x8 af[4], bfr[4];
#pragma unroll
      for (int i = 0; i < 4; i++) {
        af[i] = *(const bf16x8*)&As[(wm + i * 16 + l15) * 64 + kk + quad * 8];
        bfr[i] = *(const bf16x8*)&Bs[(wn + i * 16 + l15) * 64 + kk + quad * 8];
      }
#pragma unroll
      for (int i = 0; i < 4; i++)
#pragma unroll
        for (int j = 0; j < 4; j++)
          acc[i][j] = __builtin_amdgcn_mfma_f32_16x16x32_bf16(
              af[i], bfr[j], acc[i][j], 0, 0, 0);
    }
  }
#pragma unroll
  for (int i = 0; i < 4; i++)
#pragma unroll
    for (int r = 0; r < 4; r++) {
      int row = m0 + wm + i * 16 + quad * 4 + r;
#pragma unroll
      for (int j = 0; j < 4; j++) {
        int col = n0 + wn + j * 16 + l15;
        float v = acc[i][j][r];
        if (ADD_RES) v += Res[(size_t)row * ldr + col];
        if (OUT_BF16)
          ((unsigned short*)C)[(size_t)row * ldc + col] = f2bf(v);
        else
          ((float*)C)[(size_t)row * ldc + col] = v;
      }
    }
}

// ---------------- bf16 MFMA GEMM, 64x64 tile, split-K + optional residual --
template <bool ADD_RES>
__global__ __launch_bounds__(256) void gemm_mfma_64(
    const __hip_bfloat16* __restrict__ A, int lda,
    const __hip_bfloat16* __restrict__ Bw, int ldb,
    const float* __restrict__ Res, int ldr,
    float* __restrict__ C, int ldc, int K, size_t czs) {
  __shared__ short As[64 * 64];
  __shared__ short Bs[64 * 64];
  int t = threadIdx.x;
  int n0 = blockIdx.x * 64, m0 = blockIdx.y * 64;
  size_t kbase = (size_t)blockIdx.z * K;
  int w = t >> 6, lane = t & 63;
  int wm = (w >> 1) * 32, wn = (w & 1) * 32;
  int l15 = lane & 15, quad = lane >> 4;
  int lr = lane >> 3, lc = (lane & 7) * 8;
  const short* Ag = (const short*)A + (size_t)(m0 + w * 16 + lr) * lda + lc + kbase;
  const short* Bg = (const short*)Bw + (size_t)(n0 + w * 16 + lr) * ldb + lc + kbase;
  f32x4 acc[2][2];
#pragma unroll
  for (int i = 0; i < 2; i++)
#pragma unroll
    for (int j = 0; j < 2; j++) acc[i][j] = (f32x4){0.f, 0.f, 0.f, 0.f};
  for (int k0 = 0; k0 < K; k0 += 64) {
    __syncthreads();
#pragma unroll
    for (int p = 0; p < 2; p++) {
      gload16(Ag + (size_t)(p * 8) * lda + k0, &As[(w * 16 + p * 8) * 64]);
      gload16(Bg + (size_t)(p * 8) * ldb + k0, &Bs[(w * 16 + p * 8) * 64]);
    }
    __syncthreads();
#pragma unroll
    for (int kk = 0; kk < 64; kk += 32) {
      bf16x8 af[2], bfr[2];
#pragma unroll
      for (int i = 0; i < 2; i++) {
        af[i] = *(const bf16x8*)&As[(wm + i * 16 + l15) * 64 + kk + quad * 8];
        bfr[i] = *(const bf16x8*)&Bs[(wn + i * 16 + l15) * 64 + kk + quad * 8];
      }
#pragma unroll
      for (int i = 0; i < 2; i++)
#pragma unroll
        for (int j = 0; j < 2; j++)
          acc[i][j] = __builtin_amdgcn_mfma_f32_16x16x32_bf16(
              af[i], bfr[j], acc[i][j], 0, 0, 0);
    }
  }
  float* Cz = C + czs * blockIdx.z;
#pragma unroll
  for (int i = 0; i < 2; i++)
#pragma unroll
    for (int r = 0; r < 4; r++) {
      int row = m0 + wm + i * 16 + quad * 4 + r;
#pragma unroll
      for (int j = 0; j < 2; j++) {
        int col = n0 + wn + j * 16 + l15;
        float v = acc[i][j][r];
        if (ADD_RES) v += Res[(size_t)row * ldr + col];
        Cz[(size_t)row * ldc + col] = v;
      }
    }
}

// ------- causal depthwise conv (4 taps) + SiLU over bf16 xp ----------------
__global__ __launch_bounds__(256) void conv_silu_kernel(
    const unsigned short* __restrict__ xzb, const float* __restrict__ cw,
    const float* __restrict__ cb, __hip_bfloat16* __restrict__ xc_bf) {
  int idx = blockIdx.x * 256 + threadIdx.x;   // over BL*DINNER/4
  int d4 = (idx & 255) * 4;
  int bl = idx >> 8;
  int l = bl & (L_ - 1);
  const unsigned short* base = xzb + (size_t)bl * 2048 + d4;
  float4 acc = *(const float4*)(cb + d4);
  float4 w0 = *(const float4*)(cw + (d4 + 0) * 4);
  float4 w1 = *(const float4*)(cw + (d4 + 1) * 4);
  float4 w2 = *(const float4*)(cw + (d4 + 2) * 4);
  float4 w3 = *(const float4*)(cw + (d4 + 3) * 4);
  if (l >= 3) {
    ushort4 r = *(const ushort4*)(base - 3 * 2048);
    acc.x += bf2f(r.x) * w0.x; acc.y += bf2f(r.y) * w1.x;
    acc.z += bf2f(r.z) * w2.x; acc.w += bf2f(r.w) * w3.x;
  }
  if (l >= 2) {
    ushort4 r = *(const ushort4*)(base - 2 * 2048);
    acc.x += bf2f(r.x) * w0.y; acc.y += bf2f(r.y) * w1.y;
    acc.z += bf2f(r.z) * w2.y; acc.w += bf2f(r.w) * w3.y;
  }
  if (l >= 1) {
    ushort4 r = *(const ushort4*)(base - 1 * 2048);
    acc.x += bf2f(r.x) * w0.z; acc.y += bf2f(r.y) * w1.z;
    acc.z += bf2f(r.z) * w2.z; acc.w += bf2f(r.w) * w3.z;
  }
  {
    ushort4 r = *(const ushort4*)(base);
    acc.x += bf2f(r.x) * w0.w; acc.y += bf2f(r.y) * w1.w;
    acc.z += bf2f(r.z) * w2.w; acc.w += bf2f(r.w) * w3.w;
  }
  float4 v;
  v.x = acc.x / (1.f + __expf(-acc.x));
  v.y = acc.y / (1.f + __expf(-acc.y));
  v.z = acc.z / (1.f + __expf(-acc.z));
  v.w = acc.w / (1.f + __expf(-acc.w));
  ushort4 hb;
  hb.x = f2bf(v.x); hb.y = f2bf(v.y); hb.z = f2bf(v.z); hb.w = f2bf(v.w);
  *(ushort4*)(xc_bf + (size_t)bl * DINNER + d4) = hb;
}

// ---------------- split-K reduce: proj = sum of 8 pp slices ----------------
__global__ __launch_bounds__(256) void reduce8_kernel(
    const float* __restrict__ pp, float* __restrict__ proj) {
  int i = (blockIdx.x * 256 + threadIdx.x) * 4;   // over 262144
  float4 s = *(const float4*)(pp + i);
#pragma unroll
  for (int k = 1; k < 8; k++) {
    float4 a = *(const float4*)(pp + i + k * 262144);
    s.x += a.x; s.y += a.y; s.z += a.z; s.w += a.w;
  }
  *(float4*)(proj + i) = s;
}

// ---- scan pass 1, (d,n)-parallel: per-chunk decay T and end-state E -------
// dt computed INLINE from proj[:, :32] @ Wdt (both L2-resident) -- no dt
// array in HBM at all.
__global__ __launch_bounds__(256) void scan1_kernel(
    const __hip_bfloat16* __restrict__ xc_bf, const float* __restrict__ proj,
    const float* __restrict__ A_log, const float* __restrict__ Wdt,
    const float* __restrict__ bdt, float* __restrict__ T,
    float* __restrict__ E) {
  int bid = blockIdx.x;
  int dgrp = bid & 63;
  int c = (bid >> 6) & (NCHUNK - 1);
  int b = bid >> 12;
  int tid = threadIdx.x;
  int n = tid & 15;
  int dl = tid >> 4;
  int d = dgrp * 16 + dl;
  int l0 = c * CLEN;
  __shared__ float dts[CLEN * 16];   // [l][d]
  __shared__ float dxs[CLEN * 16];   // dt*xc, [l][d]
  __shared__ float Bsh[CLEN * 16];   // [l][n]
  for (int i = tid; i < CLEN * 16; i += 256) {
    int row = i >> 4, col = i & 15;
    size_t bl = (size_t)(b * L_ + l0 + row);
    int dcol = dgrp * 16 + col;
    const float* prow = proj + bl * 64;
    const float* wrow = Wdt + (size_t)dcol * 32;
    float a0 = 0.f, a1 = 0.f, a2 = 0.f, a3 = 0.f;
#pragma unroll
    for (int q = 0; q < 8; q++) {
      float4 pv = *(const float4*)(prow + q * 4);
      float4 wv = *(const float4*)(wrow + q * 4);
      a0 = fmaf(pv.x, wv.x, a0); a1 = fmaf(pv.y, wv.y, a1);
      a2 = fmaf(pv.z, wv.z, a2); a3 = fmaf(pv.w, wv.w, a3);
    }
    float dtv = softplus_f(bdt[dcol] + ((a0 + a1) + (a2 + a3)));
    float xv = __bfloat162float(xc_bf[bl * DINNER + dcol]);
    dts[i] = dtv;
    dxs[i] = dtv * xv;
    Bsh[i] = prow[32 + col];
  }
  float Aa = -__expf(A_log[(size_t)d * 16 + n]);
  __syncthreads();
  float Tn = 1.f, En = 0.f;
#pragma unroll 8
  for (int l = 0; l < CLEN; l++) {
    float dA = __expf(dts[l * 16 + dl] * Aa);
    Tn *= dA;
    En = En * dA + dxs[l * 16 + dl] * Bsh[l * 16 + n];
  }
  size_t o = (((size_t)b * NCHUNK + c) * DINNER + d) * 16 + n;
  T[o] = Tn; E[o] = En;
}

// ------- chunk combine: all 64 (t,e) loaded up front for max MLP -----------
__global__ __launch_bounds__(256) void combine_kernel(
    float* __restrict__ T, const float* __restrict__ E) {
  int idx = blockIdx.x * 256 + threadIdx.x;   // over B*DINNER*16 = 32768
  int b = idx >> 14;
  int dn = idx & 16383;
  size_t base = (size_t)b * NCHUNK * (DINNER * 16) + dn;
  float t[64], e[64];
#pragma unroll
  for (int j = 0; j < 64; j++) {
    size_t o = base + (size_t)j * (DINNER * 16);
    t[j] = T[o]; e[j] = E[o];
  }
  float s = 0.f;
#pragma unroll
  for (int j = 0; j < 64; j++) {
    float tj = t[j];
    t[j] = s;                  // t[] now holds chunk-start states
    s = tj * s + e[j];
  }
#pragma unroll
  for (int j = 0; j < 64; j++)
    T[base + (size_t)j * (DINNER * 16)] = t[j];
}

// ---- scan pass 2: dt inline (phase A, reg-resident), 16 states/thread -----
// gate = SiLU(z) on the fly; y written bf16 to cols 0..1023 of xz.
__global__ __launch_bounds__(256) void scan2_kernel(
    const __hip_bfloat16* __restrict__ xc_bf, const float* __restrict__ proj,
    const float* __restrict__ A_log, const float* __restrict__ Sstart,
    const float* __restrict__ Dp, const float* __restrict__ Wdt,
    const float* __restrict__ bdt, unsigned short* __restrict__ xzb) {
  int bid = blockIdx.x;
  int dgrp = bid & 3;
  int c = (bid >> 2) & (NCHUNK - 1);
  int b = bid >> 8;
  int tid = threadIdx.x;
  int d = dgrp * 256 + tid;
  int l0 = c * CLEN;
  __shared__ float Bs[CLEN * 16];
  __shared__ float Cs[CLEN * 16];
  __shared__ float Pr[CLEN * 32];    // proj[:, 0:32] rows for this chunk
  for (int i = tid; i < CLEN * 16; i += 256) {
    int row = i >> 4, nn = i & 15;
    const float* pr = proj + (size_t)(b * L_ + l0 + row) * 64;
    Bs[i] = pr[32 + nn];
    Cs[i] = pr[48 + nn];
  }
  for (int i = tid; i < CLEN * 32; i += 256) {
    int row = i >> 5, rr = i & 31;
    Pr[i] = proj[(size_t)(b * L_ + l0 + row) * 64 + rr];
  }
  float w[32];
#pragma unroll
  for (int q = 0; q < 8; q++) {
    float4 wv = *(const float4*)(Wdt + (size_t)d * 32 + q * 4);
    w[q * 4 + 0] = wv.x; w[q * 4 + 1] = wv.y;
    w[q * 4 + 2] = wv.z; w[q * 4 + 3] = wv.w;
  }
  float bias = bdt[d];
  float Aa[16], s[16];
  size_t sb = (((size_t)b * NCHUNK + c) * DINNER + d) * 16;
#pragma unroll
  for (int q = 0; q < 4; q++) {
    float4 av = *(const float4*)(A_log + (size_t)d * 16 + q * 4);
    Aa[q * 4 + 0] = -__expf(av.x); Aa[q * 4 + 1] = -__expf(av.y);
    Aa[q * 4 + 2] = -__expf(av.z); Aa[q * 4 + 3] = -__expf(av.w);
    float4 sv = *(const float4*)(Sstart + sb + q * 4);
    s[q * 4 + 0] = sv.x; s[q * 4 + 1] = sv.y;
    s[q * 4 + 2] = sv.z; s[q * 4 + 3] = sv.w;
  }
  float Dv = Dp[d];
  __syncthreads();
  // phase A: dt + xc for all 32 rows, fully parallel, reg-resident
  float dt32[CLEN], xv32[CLEN];
#pragma unroll
  for (int l = 0; l < CLEN; l++) {
    float a0 = 0.f, a1 = 0.f, a2 = 0.f, a3 = 0.f;
#pragma unroll
    for (int q = 0; q < 8; q++) {
      a0 = fmaf(Pr[l * 32 + q * 4 + 0], w[q * 4 + 0], a0);
      a1 = fmaf(Pr[l * 32 + q * 4 + 1], w[q * 4 + 1], a1);
      a2 = fmaf(Pr[l * 32 + q * 4 + 2], w[q * 4 + 2], a2);
      a3 = fmaf(Pr[l * 32 + q * 4 + 3], w[q * 4 + 3], a3);
    }
    dt32[l] = softplus_f(bias + ((a0 + a1) + (a2 + a3)));
    xv32[l] = __bfloat162float(xc_bf[(size_t)(b * L_ + l0 + l) * DINNER + d]);
  }
  // phase B: serial recurrence (fully unrolled, static reg indices)
#pragma unroll
  for (int l = 0; l < CLEN; l++) {
    int bl = b * L_ + l0 + l;
    float dtv = dt32[l];
    float xv = xv32[l];
    float dx = dtv * xv;
    float y = 0.f;
#pragma unroll
    for (int n = 0; n < 16; n++) {
      float dA = __expf(dtv * Aa[n]);
      s[n] = s[n] * dA + dx * Bs[l * 16 + n];
      y += s[n] * Cs[l * 16 + n];
    }
    float zv = bf2f(xzb[(size_t)bl * 2048 + 1024 + d]);
    float gate = zv / (1.f + __expf(-zv));
    xzb[(size_t)bl * 2048 + d] = f2bf((y + xv * Dv) * gate);
  }
}

extern "C" void kernel_launch(void* const* d_in, const int* in_sizes, int n_in,
                              void* d_out, int out_size, void* d_ws, size_t ws_size,
                              hipStream_t stream) {
  const float* x      = (const float*)d_in[0];
  const float* ln_g   = (const float*)d_in[1];
  const float* ln_b   = (const float*)d_in[2];
  const float* W_in   = (const float*)d_in[3];
  const float* conv_w = (const float*)d_in[4];
  const float* conv_b = (const float*)d_in[5];
  const float* W_xprj = (const float*)d_in[6];
  const float* W_dt   = (const float*)d_in[7];
  const float* b_dt   = (const float*)d_in[8];
  const float* A_log  = (const float*)d_in[9];
  const float* Dp     = (const float*)d_in[10];
  const float* W_out  = (const float*)d_in[11];
  float* out = (float*)d_out;

  // workspace layout (floats) -- ~58.9 MB, no aliases
  float* ws     = (float*)d_ws;
  float* xzb_f  = ws;                      // 4,194,304 f (xz bf16 [4096][2048])
  float* xcbf_f = xzb_f + 4194304;         // 2,097,152 f (xc_bf)
  float* proj   = xcbf_f + 2097152;        //   262,144 f
  float* pp     = proj + 262144;           // 2,097,152 f (8 split-K slices)
  float* T      = pp + 2097152;            // 2,097,152 f
  float* E      = T + 2097152;             // 2,097,152 f
  float* hbf_f  = E + 2097152;             // 1,048,576 f (h_bf)
  float* wbf    = hbf_f + 1048576;         //   819,200 f (bf16 weights)

  unsigned short* xzb   = (unsigned short*)xzb_f;
  __hip_bfloat16* xc_bf = (__hip_bfloat16*)xcbf_f;
  __hip_bfloat16* h_bf  = (__hip_bfloat16*)hbf_f;
  __hip_bfloat16* Wb_in = (__hip_bfloat16*)wbf;
  __hip_bfloat16* Wb_xp = Wb_in + 1048576;
  __hip_bfloat16* Wb_out = Wb_xp + 65536;
  __hip_bfloat16* y_bf  = (__hip_bfloat16*)xzb;  // cols 0..1023, lda=2048

  // 0+1. weights -> bf16  ||  LayerNorm -> bf16 h   (one dispatch)
  cvt_ln_kernel<<<1600 + BL / 4, 256, 0, stream>>>(
      W_in, W_xprj, W_out, Wb_in, Wb_xp, Wb_out, x, ln_g, ln_b, h_bf);
  // 2. xz = h @ W_in^T  (M=4096, N=2048, K=512) -> bf16 [MFMA 128x128]
  gemm_mfma_128<false, true><<<dim3(2 * DINNER / 128, BL / 128), 256, 0, stream>>>(
      h_bf, DIM_, Wb_in, DIM_, nullptr, 0, xzb, 2 * DINNER, DIM_);
  // 3. conv + SiLU -> xc_bf (z-half untouched; scan2 gates on the fly)
  conv_silu_kernel<<<(BL * DINNER / 4) / 256, 256, 0, stream>>>(
      xzb, conv_w, conv_b, xc_bf);
  // 4. proj partials = xc @ W_xproj^T (M=4096, N=64, K=1024) [64x64, split-K=8]
  gemm_mfma_64<false><<<dim3(1, BL / 64, 8), 256, 0, stream>>>(
      xc_bf, DINNER, Wb_xp, DINNER, nullptr, 0, pp, 64, 128, 262144);
  // 5. reduce pp -> proj
  reduce8_kernel<<<256, 256, 0, stream>>>(pp, proj);
  // 6. chunked scan: 64 chunks of 32 (dt computed inline in both passes)
  scan1_kernel<<<B_ * NCHUNK * 64, 256, 0, stream>>>(
      xc_bf, proj, A_log, W_dt, b_dt, T, E);
  combine_kernel<<<(B_ * DINNER * 16) / 256, 256, 0, stream>>>(T, E);
  scan2_kernel<<<B_ * NCHUNK * 4, 256, 0, stream>>>(
      xc_bf, proj, A_log, T, Dp, W_dt, b_dt, xzb);
  // 7. out = x + y @ W_out^T (M=4096, N=512, K=1024) [64x64, 512 blocks, res]
  gemm_mfma_64<true><<<dim3(DIM_ / 64, BL / 64, 1), 256, 0, stream>>>(
      y_bf, 2048, Wb_out, DINNER, x, DIM_, out, DIM_, DINNER, 0);
}

// Round 4
// 212.967 us; speedup vs baseline: 1.1121x; 1.1121x over previous
//
#include <hip/hip_runtime.h>
#include <hip/hip_bf16.h>
#include <math.h>

#define B_      2
#define L_      2048
#define DIM_    512
#define DINNER  1024
#define DTRANK  32
#define DSTATE  16
#define DCONV   4
#define BL      (B_ * L_)        // 4096
#define NCHUNK  64
#define CLEN    (L_ / NCHUNK)    // 32

typedef __attribute__((ext_vector_type(8))) short bf16x8;
typedef __attribute__((ext_vector_type(4))) float f32x4;

static __device__ __forceinline__ unsigned short f2bf(float f) {
  __hip_bfloat16 h = __float2bfloat16(f);
  return *(unsigned short*)&h;
}
static __device__ __forceinline__ float bf2f(unsigned short u) {
  return __uint_as_float(((unsigned int)u) << 16);
}

// async global->LDS, 16B per lane. LDS dest must be the WAVE-UNIFORM base;
// HW writes lane l at base + l*16 (linear, no scatter).
static __device__ __forceinline__ void gload16(const void* g, void* l) {
  __builtin_amdgcn_global_load_lds(
      (const __attribute__((address_space(1))) void*)g,
      (__attribute__((address_space(3))) void*)l, 16, 0, 0);
}

// softplus via HW exp/log
static __device__ __forceinline__ float softplus_f(float acc) {
  return (acc > 20.f) ? acc : __logf(1.f + __expf(acc));
}

// ------- merged: weight fp32->bf16 conversion + LayerNorm ------------------
__global__ __launch_bounds__(256) void cvt_ln_kernel(
    const float* __restrict__ s0, const float* __restrict__ s1,
    const float* __restrict__ s2, __hip_bfloat16* __restrict__ d0,
    __hip_bfloat16* __restrict__ d1, __hip_bfloat16* __restrict__ d2,
    const float* __restrict__ x, const float* __restrict__ g,
    const float* __restrict__ b, __hip_bfloat16* __restrict__ h) {
  int blk = blockIdx.x;
  if (blk < 1600) {
    int i = (blk * 256 + threadIdx.x) * 4;
    const float* s; __hip_bfloat16* d; int off;
    if (i < 1048576)            { s = s0; d = d0; off = i; }
    else if (i < 1048576+65536) { s = s1; d = d1; off = i - 1048576; }
    else                        { s = s2; d = d2; off = i - 1114112; }
    float4 v = *(const float4*)(s + off);
    d[off + 0] = __float2bfloat16(v.x);
    d[off + 1] = __float2bfloat16(v.y);
    d[off + 2] = __float2bfloat16(v.z);
    d[off + 3] = __float2bfloat16(v.w);
    return;
  }
  int row = (blk - 1600) * 4 + (threadIdx.x >> 6);
  int lane = threadIdx.x & 63;
  const float* xr = x + (size_t)row * DIM_;
  float v[8];
  float sum = 0.f;
#pragma unroll
  for (int i = 0; i < 8; i++) { v[i] = xr[lane + i * 64]; sum += v[i]; }
#pragma unroll
  for (int o = 32; o > 0; o >>= 1) sum += __shfl_xor(sum, o, 64);
  float mu = sum * (1.f / DIM_);
  float vs = 0.f;
#pragma unroll
  for (int i = 0; i < 8; i++) { float dd = v[i] - mu; vs += dd * dd; }
#pragma unroll
  for (int o = 32; o > 0; o >>= 1) vs += __shfl_xor(vs, o, 64);
  float rstd = rsqrtf(vs * (1.f / DIM_) + 1e-5f);
  __hip_bfloat16* hr = h + (size_t)row * DIM_;
#pragma unroll
  for (int i = 0; i < 8; i++) {
    int c = lane + i * 64;
    hr[c] = __float2bfloat16((v[i] - mu) * rstd * g[c] + b[c]);
  }
}

// ---------------- bf16 MFMA GEMM, 128x128 tile: C = A[M,K] * B[N,K]^T ------
template <bool ADD_RES, bool OUT_BF16>
__global__ __launch_bounds__(256) void gemm_mfma_128(
    const __hip_bfloat16* __restrict__ A, int lda,
    const __hip_bfloat16* __restrict__ Bw, int ldb,
    const float* __restrict__ Res, int ldr,
    void* __restrict__ C, int ldc, int K) {
  __shared__ short As[128 * 64];
  __shared__ short Bs[128 * 64];
  int t = threadIdx.x;
  int n0 = blockIdx.x * 128, m0 = blockIdx.y * 128;
  int w = t >> 6, lane = t & 63;
  int wm = (w >> 1) * 64, wn = (w & 1) * 64;
  int l15 = lane & 15, quad = lane >> 4;
  int lr = lane >> 3, lc = (lane & 7) * 8;
  const short* Ag = (const short*)A + (size_t)(m0 + w * 32 + lr) * lda + lc;
  const short* Bg = (const short*)Bw + (size_t)(n0 + w * 32 + lr) * ldb + lc;
  f32x4 acc[4][4];
#pragma unroll
  for (int i = 0; i < 4; i++)
#pragma unroll
    for (int j = 0; j < 4; j++) acc[i][j] = (f32x4){0.f, 0.f, 0.f, 0.f};
  for (int k0 = 0; k0 < K; k0 += 64) {
    __syncthreads();
#pragma unroll
    for (int p = 0; p < 4; p++) {
      gload16(Ag + (size_t)(p * 8) * lda + k0, &As[(w * 32 + p * 8) * 64]);
      gload16(Bg + (size_t)(p * 8) * ldb + k0, &Bs[(w * 32 + p * 8) * 64]);
    }
    __syncthreads();
#pragma unroll
    for (int kk = 0; kk < 64; kk += 32) {
      bf16x8 af[4], bfr[4];
#pragma unroll
      for (int i = 0; i < 4; i++) {
        af[i] = *(const bf16x8*)&As[(wm + i * 16 + l15) * 64 + kk + quad * 8];
        bfr[i] = *(const bf16x8*)&Bs[(wn + i * 16 + l15) * 64 + kk + quad * 8];
      }
#pragma unroll
      for (int i = 0; i < 4; i++)
#pragma unroll
        for (int j = 0; j < 4; j++)
          acc[i][j] = __builtin_amdgcn_mfma_f32_16x16x32_bf16(
              af[i], bfr[j], acc[i][j], 0, 0, 0);
    }
  }
#pragma unroll
  for (int i = 0; i < 4; i++)
#pragma unroll
    for (int r = 0; r < 4; r++) {
      int row = m0 + wm + i * 16 + quad * 4 + r;
#pragma unroll
      for (int j = 0; j < 4; j++) {
        int col = n0 + wn + j * 16 + l15;
        float v = acc[i][j][r];
        if (ADD_RES) v += Res[(size_t)row * ldr + col];
        if (OUT_BF16)
          ((unsigned short*)C)[(size_t)row * ldc + col] = f2bf(v);
        else
          ((float*)C)[(size_t)row * ldc + col] = v;
      }
    }
}

// ---------------- bf16 MFMA GEMM, 64x64 tile, split-K + optional residual --
template <bool ADD_RES>
__global__ __launch_bounds__(256) void gemm_mfma_64(
    const __hip_bfloat16* __restrict__ A, int lda,
    const __hip_bfloat16* __restrict__ Bw, int ldb,
    const float* __restrict__ Res, int ldr,
    float* __restrict__ C, int ldc, int K, size_t czs) {
  __shared__ short As[64 * 64];
  __shared__ short Bs[64 * 64];
  int t = threadIdx.x;
  int n0 = blockIdx.x * 64, m0 = blockIdx.y * 64;
  size_t kbase = (size_t)blockIdx.z * K;
  int w = t >> 6, lane = t & 63;
  int wm = (w >> 1) * 32, wn = (w & 1) * 32;
  int l15 = lane & 15, quad = lane >> 4;
  int lr = lane >> 3, lc = (lane & 7) * 8;
  const short* Ag = (const short*)A + (size_t)(m0 + w * 16 + lr) * lda + lc + kbase;
  const short* Bg = (const short*)Bw + (size_t)(n0 + w * 16 + lr) * ldb + lc + kbase;
  f32x4 acc[2][2];
#pragma unroll
  for (int i = 0; i < 2; i++)
#pragma unroll
    for (int j = 0; j < 2; j++) acc[i][j] = (f32x4){0.f, 0.f, 0.f, 0.f};
  for (int k0 = 0; k0 < K; k0 += 64) {
    __syncthreads();
#pragma unroll
    for (int p = 0; p < 2; p++) {
      gload16(Ag + (size_t)(p * 8) * lda + k0, &As[(w * 16 + p * 8) * 64]);
      gload16(Bg + (size_t)(p * 8) * ldb + k0, &Bs[(w * 16 + p * 8) * 64]);
    }
    __syncthreads();
#pragma unroll
    for (int kk = 0; kk < 64; kk += 32) {
      bf16x8 af[2], bfr[2];
#pragma unroll
      for (int i = 0; i < 2; i++) {
        af[i] = *(const bf16x8*)&As[(wm + i * 16 + l15) * 64 + kk + quad * 8];
        bfr[i] = *(const bf16x8*)&Bs[(wn + i * 16 + l15) * 64 + kk + quad * 8];
      }
#pragma unroll
      for (int i = 0; i < 2; i++)
#pragma unroll
        for (int j = 0; j < 2; j++)
          acc[i][j] = __builtin_amdgcn_mfma_f32_16x16x32_bf16(
              af[i], bfr[j], acc[i][j], 0, 0, 0);
    }
  }
  float* Cz = C + czs * blockIdx.z;
#pragma unroll
  for (int i = 0; i < 2; i++)
#pragma unroll
    for (int r = 0; r < 4; r++) {
      int row = m0 + wm + i * 16 + quad * 4 + r;
#pragma unroll
      for (int j = 0; j < 2; j++) {
        int col = n0 + wn + j * 16 + l15;
        float v = acc[i][j][r];
        if (ADD_RES) v += Res[(size_t)row * ldr + col];
        Cz[(size_t)row * ldc + col] = v;
      }
    }
}

// ------- causal depthwise conv (4 taps) + SiLU over bf16 xp ----------------
__global__ __launch_bounds__(256) void conv_silu_kernel(
    const unsigned short* __restrict__ xzb, const float* __restrict__ cw,
    const float* __restrict__ cb, __hip_bfloat16* __restrict__ xc_bf) {
  int idx = blockIdx.x * 256 + threadIdx.x;   // over BL*DINNER/4
  int d4 = (idx & 255) * 4;
  int bl = idx >> 8;
  int l = bl & (L_ - 1);
  const unsigned short* base = xzb + (size_t)bl * 2048 + d4;
  float4 acc = *(const float4*)(cb + d4);
  float4 w0 = *(const float4*)(cw + (d4 + 0) * 4);
  float4 w1 = *(const float4*)(cw + (d4 + 1) * 4);
  float4 w2 = *(const float4*)(cw + (d4 + 2) * 4);
  float4 w3 = *(const float4*)(cw + (d4 + 3) * 4);
  if (l >= 3) {
    ushort4 r = *(const ushort4*)(base - 3 * 2048);
    acc.x += bf2f(r.x) * w0.x; acc.y += bf2f(r.y) * w1.x;
    acc.z += bf2f(r.z) * w2.x; acc.w += bf2f(r.w) * w3.x;
  }
  if (l >= 2) {
    ushort4 r = *(const ushort4*)(base - 2 * 2048);
    acc.x += bf2f(r.x) * w0.y; acc.y += bf2f(r.y) * w1.y;
    acc.z += bf2f(r.z) * w2.y; acc.w += bf2f(r.w) * w3.y;
  }
  if (l >= 1) {
    ushort4 r = *(const ushort4*)(base - 1 * 2048);
    acc.x += bf2f(r.x) * w0.z; acc.y += bf2f(r.y) * w1.z;
    acc.z += bf2f(r.z) * w2.z; acc.w += bf2f(r.w) * w3.z;
  }
  {
    ushort4 r = *(const ushort4*)(base);
    acc.x += bf2f(r.x) * w0.w; acc.y += bf2f(r.y) * w1.w;
    acc.z += bf2f(r.z) * w2.w; acc.w += bf2f(r.w) * w3.w;
  }
  float4 v;
  v.x = acc.x / (1.f + __expf(-acc.x));
  v.y = acc.y / (1.f + __expf(-acc.y));
  v.z = acc.z / (1.f + __expf(-acc.z));
  v.w = acc.w / (1.f + __expf(-acc.w));
  ushort4 hb;
  hb.x = f2bf(v.x); hb.y = f2bf(v.y); hb.z = f2bf(v.z); hb.w = f2bf(v.w);
  *(ushort4*)(xc_bf + (size_t)bl * DINNER + d4) = hb;
}

// ---- split-K reduce (fused) + dt = softplus(proj[:, :32] @ W_dt^T + b_dt) -
// v3: restructured for memory-level parallelism. 2048 blocks (8 bl-rows
// each); staging = 4 independent float4 loads per lane (threads 0..127);
// Wdt/bias loads hoisted before the barrier so they overlap staging latency;
// 8 rows fully unrolled with 4 independent FMA chains each; coalesced
// float4 proj write and coalesced dt stores.
__global__ __launch_bounds__(256) void dt_kernel(
    const float* __restrict__ pp, float* __restrict__ proj,
    const float* __restrict__ Wdt, const float* __restrict__ bdt,
    float* __restrict__ dt) {
  int blk = blockIdx.x;
  int dgrp = blk & 3;
  int bl0 = (blk >> 2) * 8;              // 8 bl-rows per block
  int tid = threadIdx.x;
  int d = dgrp * 256 + tid;
  __shared__ float pr[8 * 64];
  // hoisted: weight + bias loads (independent of staging)
  float w[32];
#pragma unroll
  for (int q = 0; q < 8; q++) {
    float4 wv = *(const float4*)(Wdt + (size_t)d * 32 + q * 4);
    w[q * 4 + 0] = wv.x; w[q * 4 + 1] = wv.y;
    w[q * 4 + 2] = wv.z; w[q * 4 + 3] = wv.w;
  }
  float bias = bdt[d];
  // staging: 8 rows x 64 cols = 128 float4; threads 0..127, 4 indep loads
  if (tid < 128) {
    int o4 = bl0 * 16 + tid;             // float4 index into pp slice
    float4 v0 = ((const float4*)pp)[o4];
    float4 v1 = ((const float4*)pp)[o4 + 65536];
    float4 v2 = ((const float4*)pp)[o4 + 131072];
    float4 v3 = ((const float4*)pp)[o4 + 196608];
    float4 s;
    s.x = (v0.x + v1.x) + (v2.x + v3.x);
    s.y = (v0.y + v1.y) + (v2.y + v3.y);
    s.z = (v0.z + v1.z) + (v2.z + v3.z);
    s.w = (v0.w + v1.w) + (v2.w + v3.w);
    ((float4*)pr)[tid] = s;
    if (dgrp == 0) *(float4*)(proj + (size_t)bl0 * 64 + tid * 4) = s;
  }
  __syncthreads();
#pragma unroll
  for (int row = 0; row < 8; row++) {
    float a0 = 0.f, a1 = 0.f, a2 = 0.f, a3 = 0.f;
#pragma unroll
    for (int q = 0; q < 8; q++) {
      float4 pv = *(const float4*)&pr[row * 64 + q * 4];
      a0 = fmaf(pv.x, w[q * 4 + 0], a0);
      a1 = fmaf(pv.y, w[q * 4 + 1], a1);
      a2 = fmaf(pv.z, w[q * 4 + 2], a2);
      a3 = fmaf(pv.w, w[q * 4 + 3], a3);
    }
    float acc = bias + ((a0 + a1) + (a2 + a3));
    dt[(size_t)(bl0 + row) * DINNER + d] = softplus_f(acc);
  }
}

// ---- scan pass 1, (d,n)-parallel: per-chunk decay T and end-state E -------
// operands LDS-staged once per chunk -> recurrence is pure VALU + LDS reads.
__global__ __launch_bounds__(256) void scan1_kernel(
    const float* __restrict__ dt, const __hip_bfloat16* __restrict__ xc_bf,
    const float* __restrict__ proj, const float* __restrict__ A_log,
    float* __restrict__ T, float* __restrict__ E) {
  int bid = blockIdx.x;
  int dgrp = bid & 63;
  int c = (bid >> 6) & (NCHUNK - 1);
  int b = bid >> 12;
  int tid = threadIdx.x;
  int n = tid & 15;
  int dl = tid >> 4;
  int d = dgrp * 16 + dl;
  int l0 = c * CLEN;
  __shared__ float dts[CLEN * 16];   // [l][d]
  __shared__ float dxs[CLEN * 16];   // dt*xc, [l][d]
  __shared__ float Bsh[CLEN * 16];   // [l][n]
  for (int i = tid; i < CLEN * 16; i += 256) {
    int row = i >> 4, col = i & 15;
    size_t bl = (size_t)(b * L_ + l0 + row);
    float dtv = dt[bl * DINNER + dgrp * 16 + col];
    float xv = __bfloat162float(xc_bf[bl * DINNER + dgrp * 16 + col]);
    dts[i] = dtv;
    dxs[i] = dtv * xv;
    Bsh[i] = proj[bl * 64 + 32 + col];
  }
  float Aa = -__expf(A_log[(size_t)d * 16 + n]);
  __syncthreads();
  float Tn = 1.f, En = 0.f;
#pragma unroll 8
  for (int l = 0; l < CLEN; l++) {
    float dA = __expf(dts[l * 16 + dl] * Aa);
    Tn *= dA;
    En = En * dA + dxs[l * 16 + dl] * Bsh[l * 16 + n];
  }
  size_t o = (((size_t)b * NCHUNK + c) * DINNER + d) * 16 + n;
  T[o] = Tn; E[o] = En;
}

// ---------------- chunk combine over 64 chunks, 4 register-batches of 16 ----
__global__ __launch_bounds__(256) void combine_kernel(
    float* __restrict__ T, const float* __restrict__ E) {
  int idx = blockIdx.x * 256 + threadIdx.x;   // over B*DINNER*16 = 32768
  int b = idx >> 14;
  int dn = idx & 16383;
  size_t base = (size_t)b * NCHUNK * (DINNER * 16) + dn;
  float s = 0.f;
#pragma unroll
  for (int batch = 0; batch < 4; batch++) {
    float t[16], e[16];
#pragma unroll
    for (int j = 0; j < 16; j++) {
      size_t o = base + (size_t)(batch * 16 + j) * (DINNER * 16);
      t[j] = T[o]; e[j] = E[o];
    }
#pragma unroll
    for (int j = 0; j < 16; j++) {
      T[base + (size_t)(batch * 16 + j) * (DINNER * 16)] = s;
      s = t[j] * s + e[j];
    }
  }
}

// ---- scan pass 2: 16 states per thread, in-register y reduction -----------
// gate = SiLU(z) computed on the fly from raw z (cols 1024..2047 of xz);
// y written bf16 to cols 0..1023.
__global__ __launch_bounds__(256) void scan2_kernel(
    const float* __restrict__ dt, const __hip_bfloat16* __restrict__ xc_bf,
    const float* __restrict__ proj, const float* __restrict__ A_log,
    const float* __restrict__ Sstart, const float* __restrict__ Dp,
    unsigned short* __restrict__ xzb) {
  int bid = blockIdx.x;
  int dgrp = bid & 3;
  int c = (bid >> 2) & (NCHUNK - 1);
  int b = bid >> 8;
  int d = dgrp * 256 + threadIdx.x;
  int l0 = c * CLEN;
  __shared__ float Bs[CLEN * 16];
  __shared__ float Cs[CLEN * 16];
  for (int i = threadIdx.x; i < CLEN * 16; i += 256) {
    int row = i >> 4, nn = i & 15;
    const float* pr = proj + (size_t)(b * L_ + l0 + row) * 64;
    Bs[i] = pr[32 + nn];
    Cs[i] = pr[48 + nn];
  }
  float Aa[16], s[16];
  size_t sb = (((size_t)b * NCHUNK + c) * DINNER + d) * 16;
#pragma unroll
  for (int q = 0; q < 4; q++) {
    float4 av = *(const float4*)(A_log + (size_t)d * 16 + q * 4);
    Aa[q * 4 + 0] = -__expf(av.x); Aa[q * 4 + 1] = -__expf(av.y);
    Aa[q * 4 + 2] = -__expf(av.z); Aa[q * 4 + 3] = -__expf(av.w);
    float4 sv = *(const float4*)(Sstart + sb + q * 4);
    s[q * 4 + 0] = sv.x; s[q * 4 + 1] = sv.y;
    s[q * 4 + 2] = sv.z; s[q * 4 + 3] = sv.w;
  }
  float Dv = Dp[d];
  __syncthreads();
  for (int l = l0; l < l0 + CLEN; l++) {
    int bl = b * L_ + l;
    float dtv = dt[(size_t)bl * DINNER + d];
    float xv = __bfloat162float(xc_bf[(size_t)bl * DINNER + d]);
    float dx = dtv * xv;
    int lrow = (l - l0) * 16;
    float y = 0.f;
#pragma unroll
    for (int n = 0; n < 16; n++) {
      float dA = __expf(dtv * Aa[n]);
      s[n] = s[n] * dA + dx * Bs[lrow + n];
      y += s[n] * Cs[lrow + n];
    }
    float zv = bf2f(xzb[(size_t)bl * 2048 + 1024 + d]);
    float gate = zv / (1.f + __expf(-zv));
    xzb[(size_t)bl * 2048 + d] = f2bf((y + xv * Dv) * gate);
  }
}

extern "C" void kernel_launch(void* const* d_in, const int* in_sizes, int n_in,
                              void* d_out, int out_size, void* d_ws, size_t ws_size,
                              hipStream_t stream) {
  const float* x      = (const float*)d_in[0];
  const float* ln_g   = (const float*)d_in[1];
  const float* ln_b   = (const float*)d_in[2];
  const float* W_in   = (const float*)d_in[3];
  const float* conv_w = (const float*)d_in[4];
  const float* conv_b = (const float*)d_in[5];
  const float* W_xprj = (const float*)d_in[6];
  const float* W_dt   = (const float*)d_in[7];
  const float* b_dt   = (const float*)d_in[8];
  const float* A_log  = (const float*)d_in[9];
  const float* Dp     = (const float*)d_in[10];
  const float* W_out  = (const float*)d_in[11];
  float* out = (float*)d_out;

  // workspace layout (floats) -- no aliases (dt does not overlap pp:
  // dt_kernel reads pp while writing dt)
  float* ws     = (float*)d_ws;
  float* xzb_f  = ws;                      // 4,194,304 f (xz bf16 [4096][2048])
  float* xcbf_f = xzb_f + 4194304;         // 2,097,152 f (xc_bf)
  float* proj   = xcbf_f + 2097152;        //   262,144 f
  float* pp     = proj + 262144;           // 1,048,576 f split-K partials
  float* dtb    = pp + 1048576;            // 4,194,304 f
  float* T      = dtb + 4194304;           // 2,097,152 f
  float* E      = T + 2097152;             // 2,097,152 f
  float* hbf_f  = E + 2097152;             // 1,048,576 f (h_bf)
  float* wbf    = hbf_f + 1048576;         //   819,200 f (bf16 weights)

  unsigned short* xzb   = (unsigned short*)xzb_f;
  __hip_bfloat16* xc_bf = (__hip_bfloat16*)xcbf_f;
  __hip_bfloat16* h_bf  = (__hip_bfloat16*)hbf_f;
  __hip_bfloat16* Wb_in = (__hip_bfloat16*)wbf;
  __hip_bfloat16* Wb_xp = Wb_in + 1048576;
  __hip_bfloat16* Wb_out = Wb_xp + 65536;
  __hip_bfloat16* y_bf  = (__hip_bfloat16*)xzb;  // cols 0..1023, lda=2048

  // 0+1. weights -> bf16  ||  LayerNorm -> bf16 h   (one dispatch)
  cvt_ln_kernel<<<1600 + BL / 4, 256, 0, stream>>>(
      W_in, W_xprj, W_out, Wb_in, Wb_xp, Wb_out, x, ln_g, ln_b, h_bf);
  // 2. xz = h @ W_in^T  (M=4096, N=2048, K=512) -> bf16 [MFMA 128x128]
  gemm_mfma_128<false, true><<<dim3(2 * DINNER / 128, BL / 128), 256, 0, stream>>>(
      h_bf, DIM_, Wb_in, DIM_, nullptr, 0, xzb, 2 * DINNER, DIM_);
  // 3. conv + SiLU -> xc_bf (z-half untouched; scan2 gates on the fly)
  conv_silu_kernel<<<(BL * DINNER / 4) / 256, 256, 0, stream>>>(
      xzb, conv_w, conv_b, xc_bf);
  // 4. proj partials = xc @ W_xproj^T (M=4096, N=64, K=1024) [64x64, split-K=4]
  gemm_mfma_64<false><<<dim3(1, BL / 64, 4), 256, 0, stream>>>(
      xc_bf, DINNER, Wb_xp, DINNER, nullptr, 0, pp, 64, 256, 262144);
  // 5. fused: reduce pp -> proj  +  dt = softplus(proj[:, :32] @ W_dt^T + b_dt)
  //    v3: 2048 blocks, 8 rows each, MLP-restructured
  dt_kernel<<<(BL / 8) * 4, 256, 0, stream>>>(pp, proj, W_dt, b_dt, dtb);
  // 6. chunked scan: 64 chunks of 32
  scan1_kernel<<<B_ * NCHUNK * 64, 256, 0, stream>>>(dtb, xc_bf, proj, A_log, T, E);
  combine_kernel<<<(B_ * DINNER * 16) / 256, 256, 0, stream>>>(T, E);
  scan2_kernel<<<B_ * NCHUNK * 4, 256, 0, stream>>>(dtb, xc_bf, proj, A_log, T, Dp, xzb);
  // 7. out = x + y @ W_out^T (M=4096, N=512, K=1024) [64x64, 512 blocks, res]
  gemm_mfma_64<true><<<dim3(DIM_ / 64, BL / 64, 1), 256, 0, stream>>>(
      y_bf, 2048, Wb_out, DINNER, x, DIM_, out, DIM_, DINNER, 0);
}

// Round 5
// 190.874 us; speedup vs baseline: 1.2408x; 1.1157x over previous
//
#include <hip/hip_runtime.h>
#include <hip/hip_bf16.h>
#include <math.h>

#define B_      2
#define L_      2048
#define DIM_    512
#define DINNER  1024
#define DTRANK  32
#define DSTATE  16
#define DCONV   4
#define BL      (B_ * L_)        // 4096
#define NCHUNK  64
#define CLEN    (L_ / NCHUNK)    // 32

typedef __attribute__((ext_vector_type(8))) short bf16x8;
typedef __attribute__((ext_vector_type(4))) float f32x4;

static __device__ __forceinline__ unsigned short f2bf(float f) {
  __hip_bfloat16 h = __float2bfloat16(f);
  return *(unsigned short*)&h;
}
static __device__ __forceinline__ float bf2f(unsigned short u) {
  return __uint_as_float(((unsigned int)u) << 16);
}

// async global->LDS, 16B per lane. LDS dest must be the WAVE-UNIFORM base;
// HW writes lane l at base + l*16 (linear, no scatter).
static __device__ __forceinline__ void gload16(const void* g, void* l) {
  __builtin_amdgcn_global_load_lds(
      (const __attribute__((address_space(1))) void*)g,
      (__attribute__((address_space(3))) void*)l, 16, 0, 0);
}

// softplus via HW exp/log
static __device__ __forceinline__ float softplus_f(float acc) {
  return (acc > 20.f) ? acc : __logf(1.f + __expf(acc));
}

// ------- merged: weight fp32->bf16 conversion + LayerNorm ------------------
__global__ __launch_bounds__(256) void cvt_ln_kernel(
    const float* __restrict__ s0, const float* __restrict__ s1,
    const float* __restrict__ s2, __hip_bfloat16* __restrict__ d0,
    __hip_bfloat16* __restrict__ d1, __hip_bfloat16* __restrict__ d2,
    const float* __restrict__ x, const float* __restrict__ g,
    const float* __restrict__ b, __hip_bfloat16* __restrict__ h) {
  int blk = blockIdx.x;
  if (blk < 1600) {
    int i = (blk * 256 + threadIdx.x) * 4;
    const float* s; __hip_bfloat16* d; int off;
    if (i < 1048576)            { s = s0; d = d0; off = i; }
    else if (i < 1048576+65536) { s = s1; d = d1; off = i - 1048576; }
    else                        { s = s2; d = d2; off = i - 1114112; }
    float4 v = *(const float4*)(s + off);
    d[off + 0] = __float2bfloat16(v.x);
    d[off + 1] = __float2bfloat16(v.y);
    d[off + 2] = __float2bfloat16(v.z);
    d[off + 3] = __float2bfloat16(v.w);
    return;
  }
  int row = (blk - 1600) * 4 + (threadIdx.x >> 6);
  int lane = threadIdx.x & 63;
  const float* xr = x + (size_t)row * DIM_;
  float v[8];
  float sum = 0.f;
#pragma unroll
  for (int i = 0; i < 8; i++) { v[i] = xr[lane + i * 64]; sum += v[i]; }
#pragma unroll
  for (int o = 32; o > 0; o >>= 1) sum += __shfl_xor(sum, o, 64);
  float mu = sum * (1.f / DIM_);
  float vs = 0.f;
#pragma unroll
  for (int i = 0; i < 8; i++) { float dd = v[i] - mu; vs += dd * dd; }
#pragma unroll
  for (int o = 32; o > 0; o >>= 1) vs += __shfl_xor(vs, o, 64);
  float rstd = rsqrtf(vs * (1.f / DIM_) + 1e-5f);
  __hip_bfloat16* hr = h + (size_t)row * DIM_;
#pragma unroll
  for (int i = 0; i < 8; i++) {
    int c = lane + i * 64;
    hr[c] = __float2bfloat16((v[i] - mu) * rstd * g[c] + b[c]);
  }
}

// ---------------- bf16 MFMA GEMM, 128x128 tile: C = A[M,K] * B[N,K]^T ------
template <bool ADD_RES, bool OUT_BF16>
__global__ __launch_bounds__(256) void gemm_mfma_128(
    const __hip_bfloat16* __restrict__ A, int lda,
    const __hip_bfloat16* __restrict__ Bw, int ldb,
    const float* __restrict__ Res, int ldr,
    void* __restrict__ C, int ldc, int K) {
  __shared__ short As[128 * 64];
  __shared__ short Bs[128 * 64];
  int t = threadIdx.x;
  int n0 = blockIdx.x * 128, m0 = blockIdx.y * 128;
  int w = t >> 6, lane = t & 63;
  int wm = (w >> 1) * 64, wn = (w & 1) * 64;
  int l15 = lane & 15, quad = lane >> 4;
  int lr = lane >> 3, lc = (lane & 7) * 8;
  const short* Ag = (const short*)A + (size_t)(m0 + w * 32 + lr) * lda + lc;
  const short* Bg = (const short*)Bw + (size_t)(n0 + w * 32 + lr) * ldb + lc;
  f32x4 acc[4][4];
#pragma unroll
  for (int i = 0; i < 4; i++)
#pragma unroll
    for (int j = 0; j < 4; j++) acc[i][j] = (f32x4){0.f, 0.f, 0.f, 0.f};
  for (int k0 = 0; k0 < K; k0 += 64) {
    __syncthreads();
#pragma unroll
    for (int p = 0; p < 4; p++) {
      gload16(Ag + (size_t)(p * 8) * lda + k0, &As[(w * 32 + p * 8) * 64]);
      gload16(Bg + (size_t)(p * 8) * ldb + k0, &Bs[(w * 32 + p * 8) * 64]);
    }
    __syncthreads();
#pragma unroll
    for (int kk = 0; kk < 64; kk += 32) {
      bf16x8 af[4], bfr[4];
#pragma unroll
      for (int i = 0; i < 4; i++) {
        af[i] = *(const bf16x8*)&As[(wm + i * 16 + l15) * 64 + kk + quad * 8];
        bfr[i] = *(const bf16x8*)&Bs[(wn + i * 16 + l15) * 64 + kk + quad * 8];
      }
#pragma unroll
      for (int i = 0; i < 4; i++)
#pragma unroll
        for (int j = 0; j < 4; j++)
          acc[i][j] = __builtin_amdgcn_mfma_f32_16x16x32_bf16(
              af[i], bfr[j], acc[i][j], 0, 0, 0);
    }
  }
#pragma unroll
  for (int i = 0; i < 4; i++)
#pragma unroll
    for (int r = 0; r < 4; r++) {
      int row = m0 + wm + i * 16 + quad * 4 + r;
#pragma unroll
      for (int j = 0; j < 4; j++) {
        int col = n0 + wn + j * 16 + l15;
        float v = acc[i][j][r];
        if (ADD_RES) v += Res[(size_t)row * ldr + col];
        if (OUT_BF16)
          ((unsigned short*)C)[(size_t)row * ldc + col] = f2bf(v);
        else
          ((float*)C)[(size_t)row * ldc + col] = v;
      }
    }
}

// ---------------- bf16 MFMA GEMM, 64x64 tile, split-K + optional residual --
template <bool ADD_RES>
__global__ __launch_bounds__(256) void gemm_mfma_64(
    const __hip_bfloat16* __restrict__ A, int lda,
    const __hip_bfloat16* __restrict__ Bw, int ldb,
    const float* __restrict__ Res, int ldr,
    float* __restrict__ C, int ldc, int K, size_t czs) {
  __shared__ short As[64 * 64];
  __shared__ short Bs[64 * 64];
  int t = threadIdx.x;
  int n0 = blockIdx.x * 64, m0 = blockIdx.y * 64;
  size_t kbase = (size_t)blockIdx.z * K;
  int w = t >> 6, lane = t & 63;
  int wm = (w >> 1) * 32, wn = (w & 1) * 32;
  int l15 = lane & 15, quad = lane >> 4;
  int lr = lane >> 3, lc = (lane & 7) * 8;
  const short* Ag = (const short*)A + (size_t)(m0 + w * 16 + lr) * lda + lc + kbase;
  const short* Bg = (const short*)Bw + (size_t)(n0 + w * 16 + lr) * ldb + lc + kbase;
  f32x4 acc[2][2];
#pragma unroll
  for (int i = 0; i < 2; i++)
#pragma unroll
    for (int j = 0; j < 2; j++) acc[i][j] = (f32x4){0.f, 0.f, 0.f, 0.f};
  for (int k0 = 0; k0 < K; k0 += 64) {
    __syncthreads();
#pragma unroll
    for (int p = 0; p < 2; p++) {
      gload16(Ag + (size_t)(p * 8) * lda + k0, &As[(w * 16 + p * 8) * 64]);
      gload16(Bg + (size_t)(p * 8) * ldb + k0, &Bs[(w * 16 + p * 8) * 64]);
    }
    __syncthreads();
#pragma unroll
    for (int kk = 0; kk < 64; kk += 32) {
      bf16x8 af[2], bfr[2];
#pragma unroll
      for (int i = 0; i < 2; i++) {
        af[i] = *(const bf16x8*)&As[(wm + i * 16 + l15) * 64 + kk + quad * 8];
        bfr[i] = *(const bf16x8*)&Bs[(wn + i * 16 + l15) * 64 + kk + quad * 8];
      }
#pragma unroll
      for (int i = 0; i < 2; i++)
#pragma unroll
        for (int j = 0; j < 2; j++)
          acc[i][j] = __builtin_amdgcn_mfma_f32_16x16x32_bf16(
              af[i], bfr[j], acc[i][j], 0, 0, 0);
    }
  }
  float* Cz = C + czs * blockIdx.z;
#pragma unroll
  for (int i = 0; i < 2; i++)
#pragma unroll
    for (int r = 0; r < 4; r++) {
      int row = m0 + wm + i * 16 + quad * 4 + r;
#pragma unroll
      for (int j = 0; j < 2; j++) {
        int col = n0 + wn + j * 16 + l15;
        float v = acc[i][j][r];
        if (ADD_RES) v += Res[(size_t)row * ldr + col];
        Cz[(size_t)row * ldc + col] = v;
      }
    }
}

// ---- FUSED: conv(4-tap causal)+SiLU folded into proj GEMM A-staging -------
// A[bl][d] = silu(conv(xz_x)) computed in registers from raw xz, written to
// linear LDS + side-written ONCE to xc_bf (each (bl,d) appears in exactly
// one block: grid.y covers bl-tiles, grid.z covers disjoint d-slices).
// B = W_xproj (gload_lds). Output: pp split-K slice [4096][64].
__global__ __launch_bounds__(256) void gemm_proj_conv(
    const unsigned short* __restrict__ xzb,   // [4096][2048] bf16
    const __hip_bfloat16* __restrict__ Bw,    // Wb_xp [64][1024]
    const float* __restrict__ cw, const float* __restrict__ cb,
    __hip_bfloat16* __restrict__ xc_bf,       // side output [4096][1024]
    float* __restrict__ C, size_t czs) {
  __shared__ short As[64 * 64];
  __shared__ short Bs[64 * 64];
  __shared__ float cws[256 * 4];
  __shared__ float cbs[256];
  int t = threadIdx.x;
  int m0 = blockIdx.y * 64;
  int kbase = blockIdx.z * 256;           // d-slice base
  int w = t >> 6, lane = t & 63;
  int wm = (w >> 1) * 32, wn = (w & 1) * 32;
  int l15 = lane & 15, quad = lane >> 4;
  int lrB = lane >> 3, lcB = (lane & 7) * 8;
  const short* Bg = (const short*)Bw + (size_t)(w * 16 + lrB) * DINNER + lcB + kbase;
  // conv weights/bias for this 256-d slice -> LDS (once)
  *(float4*)&cws[t * 4] = *(const float4*)(cw + (size_t)(kbase + t) * 4);
  cbs[t] = cb[kbase + t];
  // A staging assignment: row ar (0..63), col-quad aq -> 16 cols
  int ar = t >> 2, aq = t & 3;
  int bl = m0 + ar;
  int l = bl & (L_ - 1);
  f32x4 acc[2][2];
#pragma unroll
  for (int i = 0; i < 2; i++)
#pragma unroll
    for (int j = 0; j < 2; j++) acc[i][j] = (f32x4){0.f, 0.f, 0.f, 0.f};
  for (int k0 = 0; k0 < 256; k0 += 64) {
    __syncthreads();
#pragma unroll
    for (int p = 0; p < 2; p++)
      gload16(Bg + k0 + (size_t)(p * 8) * DINNER, &Bs[(w * 16 + p * 8) * 64]);
    // conv + silu for 16 cols
    int dl0 = k0 + aq * 16;                 // local d in [0,256)
    const unsigned short* xrow = xzb + (size_t)bl * 2048 + kbase + dl0;
    float o[16];
#pragma unroll
    for (int cc = 0; cc < 16; cc++) o[cc] = cbs[dl0 + cc];
#pragma unroll
    for (int k = 0; k < 4; k++) {
      int off = 3 - k;                       // rows back
      bool ok = (l >= off);
      const unsigned short* src = xrow - (size_t)(ok ? off : 0) * 2048;
      bf16x8 v0 = *(const bf16x8*)(src);
      bf16x8 v1 = *(const bf16x8*)(src + 8);
#pragma unroll
      for (int cc = 0; cc < 8; cc++) {
        float xa = ok ? bf2f((unsigned short)v0[cc]) : 0.f;
        float xb = ok ? bf2f((unsigned short)v1[cc]) : 0.f;
        o[cc]     = fmaf(xa, cws[(dl0 + cc) * 4 + k], o[cc]);
        o[cc + 8] = fmaf(xb, cws[(dl0 + cc + 8) * 4 + k], o[cc + 8]);
      }
    }
    bf16x8 pa, pb;
#pragma unroll
    for (int cc = 0; cc < 8; cc++) {
      float va = o[cc] / (1.f + __expf(-o[cc]));
      float vb = o[cc + 8] / (1.f + __expf(-o[cc + 8]));
      pa[cc] = (short)f2bf(va);
      pb[cc] = (short)f2bf(vb);
    }
    *(bf16x8*)&As[ar * 64 + aq * 16] = pa;
    *(bf16x8*)&As[ar * 64 + aq * 16 + 8] = pb;
    // side-write xc_bf (each (bl,d) staged exactly once across the grid)
    unsigned short* xcd = (unsigned short*)xc_bf + (size_t)bl * DINNER + kbase + dl0;
    *(bf16x8*)xcd = pa;
    *(bf16x8*)(xcd + 8) = pb;
    __syncthreads();
#pragma unroll
    for (int kk = 0; kk < 64; kk += 32) {
      bf16x8 af[2], bfr[2];
#pragma unroll
      for (int i = 0; i < 2; i++) {
        af[i] = *(const bf16x8*)&As[(wm + i * 16 + l15) * 64 + kk + quad * 8];
        bfr[i] = *(const bf16x8*)&Bs[(wn + i * 16 + l15) * 64 + kk + quad * 8];
      }
#pragma unroll
      for (int i = 0; i < 2; i++)
#pragma unroll
        for (int j = 0; j < 2; j++)
          acc[i][j] = __builtin_amdgcn_mfma_f32_16x16x32_bf16(
              af[i], bfr[j], acc[i][j], 0, 0, 0);
    }
  }
  float* Cz = C + czs * blockIdx.z;
#pragma unroll
  for (int i = 0; i < 2; i++)
#pragma unroll
    for (int r = 0; r < 4; r++) {
      int row = m0 + wm + i * 16 + quad * 4 + r;
#pragma unroll
      for (int j = 0; j < 2; j++) {
        int col = wn + j * 16 + l15;
        Cz[(size_t)row * 64 + col] = acc[i][j][r];
      }
    }
}

// ---- split-K reduce (fused) + dt = softplus(proj[:, :32] @ W_dt^T + b_dt) -
__global__ __launch_bounds__(256) void dt_kernel(
    const float* __restrict__ pp, float* __restrict__ proj,
    const float* __restrict__ Wdt, const float* __restrict__ bdt,
    float* __restrict__ dt) {
  int blk = blockIdx.x;
  int dgrp = blk & 3;
  int bl0 = (blk >> 2) * 8;              // 8 bl-rows per block
  int tid = threadIdx.x;
  int d = dgrp * 256 + tid;
  __shared__ float pr[8 * 64];
  float w[32];
#pragma unroll
  for (int q = 0; q < 8; q++) {
    float4 wv = *(const float4*)(Wdt + (size_t)d * 32 + q * 4);
    w[q * 4 + 0] = wv.x; w[q * 4 + 1] = wv.y;
    w[q * 4 + 2] = wv.z; w[q * 4 + 3] = wv.w;
  }
  float bias = bdt[d];
  if (tid < 128) {
    int o4 = bl0 * 16 + tid;             // float4 index into pp slice
    float4 v0 = ((const float4*)pp)[o4];
    float4 v1 = ((const float4*)pp)[o4 + 65536];
    float4 v2 = ((const float4*)pp)[o4 + 131072];
    float4 v3 = ((const float4*)pp)[o4 + 196608];
    float4 s;
    s.x = (v0.x + v1.x) + (v2.x + v3.x);
    s.y = (v0.y + v1.y) + (v2.y + v3.y);
    s.z = (v0.z + v1.z) + (v2.z + v3.z);
    s.w = (v0.w + v1.w) + (v2.w + v3.w);
    ((float4*)pr)[tid] = s;
    if (dgrp == 0) *(float4*)(proj + (size_t)bl0 * 64 + tid * 4) = s;
  }
  __syncthreads();
#pragma unroll
  for (int row = 0; row < 8; row++) {
    float a0 = 0.f, a1 = 0.f, a2 = 0.f, a3 = 0.f;
#pragma unroll
    for (int q = 0; q < 8; q++) {
      float4 pv = *(const float4*)&pr[row * 64 + q * 4];
      a0 = fmaf(pv.x, w[q * 4 + 0], a0);
      a1 = fmaf(pv.y, w[q * 4 + 1], a1);
      a2 = fmaf(pv.z, w[q * 4 + 2], a2);
      a3 = fmaf(pv.w, w[q * 4 + 3], a3);
    }
    float acc = bias + ((a0 + a1) + (a2 + a3));
    dt[(size_t)(bl0 + row) * DINNER + d] = softplus_f(acc);
  }
}

// ---- scan pass 1, (d,n)-parallel: per-chunk decay T and end-state E -------
__global__ __launch_bounds__(256) void scan1_kernel(
    const float* __restrict__ dt, const __hip_bfloat16* __restrict__ xc_bf,
    const float* __restrict__ proj, const float* __restrict__ A_log,
    float* __restrict__ T, float* __restrict__ E) {
  int bid = blockIdx.x;
  int dgrp = bid & 63;
  int c = (bid >> 6) & (NCHUNK - 1);
  int b = bid >> 12;
  int tid = threadIdx.x;
  int n = tid & 15;
  int dl = tid >> 4;
  int d = dgrp * 16 + dl;
  int l0 = c * CLEN;
  __shared__ float dts[CLEN * 16];   // [l][d]
  __shared__ float dxs[CLEN * 16];   // dt*xc, [l][d]
  __shared__ float Bsh[CLEN * 16];   // [l][n]
  for (int i = tid; i < CLEN * 16; i += 256) {
    int row = i >> 4, col = i & 15;
    size_t bl = (size_t)(b * L_ + l0 + row);
    float dtv = dt[bl * DINNER + dgrp * 16 + col];
    float xv = __bfloat162float(xc_bf[bl * DINNER + dgrp * 16 + col]);
    dts[i] = dtv;
    dxs[i] = dtv * xv;
    Bsh[i] = proj[bl * 64 + 32 + col];
  }
  float Aa = -__expf(A_log[(size_t)d * 16 + n]);
  __syncthreads();
  float Tn = 1.f, En = 0.f;
#pragma unroll 8
  for (int l = 0; l < CLEN; l++) {
    float dA = __expf(dts[l * 16 + dl] * Aa);
    Tn *= dA;
    En = En * dA + dxs[l * 16 + dl] * Bsh[l * 16 + n];
  }
  size_t o = (((size_t)b * NCHUNK + c) * DINNER + d) * 16 + n;
  T[o] = Tn; E[o] = En;
}

// ---------------- chunk combine over 64 chunks, 4 register-batches of 16 ----
__global__ __launch_bounds__(256) void combine_kernel(
    float* __restrict__ T, const float* __restrict__ E) {
  int idx = blockIdx.x * 256 + threadIdx.x;   // over B*DINNER*16 = 32768
  int b = idx >> 14;
  int dn = idx & 16383;
  size_t base = (size_t)b * NCHUNK * (DINNER * 16) + dn;
  float s = 0.f;
#pragma unroll
  for (int batch = 0; batch < 4; batch++) {
    float t[16], e[16];
#pragma unroll
    for (int j = 0; j < 16; j++) {
      size_t o = base + (size_t)(batch * 16 + j) * (DINNER * 16);
      t[j] = T[o]; e[j] = E[o];
    }
#pragma unroll
    for (int j = 0; j < 16; j++) {
      T[base + (size_t)(batch * 16 + j) * (DINNER * 16)] = s;
      s = t[j] * s + e[j];
    }
  }
}

// ---- scan pass 2 v2: ALL global loads hoisted to registers before the -----
// serial loop (dt/xc/z: 96 independent coalesced loads). The loop is pure
// VALU + LDS; y-stores are fire-and-forget (no aliased loads follow, so no
// per-step vmcnt drain from the xzb load/store aliasing).
__global__ __launch_bounds__(256) void scan2_kernel(
    const float* __restrict__ dt, const __hip_bfloat16* __restrict__ xc_bf,
    const float* __restrict__ proj, const float* __restrict__ A_log,
    const float* __restrict__ Sstart, const float* __restrict__ Dp,
    unsigned short* __restrict__ xzb) {
  int bid = blockIdx.x;
  int dgrp = bid & 3;
  int c = (bid >> 2) & (NCHUNK - 1);
  int b = bid >> 8;
  int tid = threadIdx.x;
  int d = dgrp * 256 + tid;
  int l0 = c * CLEN;
  __shared__ float Bsh[CLEN * 16];
  __shared__ float Csh[CLEN * 16];
  for (int i = tid; i < CLEN * 16; i += 256) {
    int row = i >> 4, nn = i & 15;
    const float* pr = proj + (size_t)(b * L_ + l0 + row) * 64;
    Bsh[i] = pr[32 + nn];
    Csh[i] = pr[48 + nn];
  }
  // register preload of the full chunk (coalesced per-row, all independent)
  float dtr[CLEN], xvr[CLEN];
  unsigned short zr[CLEN];
#pragma unroll
  for (int l = 0; l < CLEN; l++) {
    size_t bl = (size_t)(b * L_ + l0 + l);
    dtr[l] = dt[bl * DINNER + d];
    xvr[l] = __bfloat162float(xc_bf[bl * DINNER + d]);
    zr[l] = xzb[bl * 2048 + 1024 + d];
  }
  float Aa[16], s[16];
  size_t sb = (((size_t)b * NCHUNK + c) * DINNER + d) * 16;
#pragma unroll
  for (int q = 0; q < 4; q++) {
    float4 av = *(const float4*)(A_log + (size_t)d * 16 + q * 4);
    Aa[q * 4 + 0] = -__expf(av.x); Aa[q * 4 + 1] = -__expf(av.y);
    Aa[q * 4 + 2] = -__expf(av.z); Aa[q * 4 + 3] = -__expf(av.w);
    float4 sv = *(const float4*)(Sstart + sb + q * 4);
    s[q * 4 + 0] = sv.x; s[q * 4 + 1] = sv.y;
    s[q * 4 + 2] = sv.z; s[q * 4 + 3] = sv.w;
  }
  float Dv = Dp[d];
  __syncthreads();
#pragma unroll
  for (int l = 0; l < CLEN; l++) {
    float dtv = dtr[l];
    float xv = xvr[l];
    float dx = dtv * xv;
    float y = 0.f;
#pragma unroll
    for (int n = 0; n < 16; n++) {
      float dA = __expf(dtv * Aa[n]);
      s[n] = s[n] * dA + dx * Bsh[l * 16 + n];
      y += s[n] * Csh[l * 16 + n];
    }
    float zv = bf2f(zr[l]);
    float gate = zv / (1.f + __expf(-zv));
    xzb[(size_t)(b * L_ + l0 + l) * 2048 + d] = f2bf((y + xv * Dv) * gate);
  }
}

extern "C" void kernel_launch(void* const* d_in, const int* in_sizes, int n_in,
                              void* d_out, int out_size, void* d_ws, size_t ws_size,
                              hipStream_t stream) {
  const float* x      = (const float*)d_in[0];
  const float* ln_g   = (const float*)d_in[1];
  const float* ln_b   = (const float*)d_in[2];
  const float* W_in   = (const float*)d_in[3];
  const float* conv_w = (const float*)d_in[4];
  const float* conv_b = (const float*)d_in[5];
  const float* W_xprj = (const float*)d_in[6];
  const float* W_dt   = (const float*)d_in[7];
  const float* b_dt   = (const float*)d_in[8];
  const float* A_log  = (const float*)d_in[9];
  const float* Dp     = (const float*)d_in[10];
  const float* W_out  = (const float*)d_in[11];
  float* out = (float*)d_out;

  // workspace layout (floats) -- no aliases
  float* ws     = (float*)d_ws;
  float* xzb_f  = ws;                      // 4,194,304 f (xz bf16 [4096][2048])
  float* xcbf_f = xzb_f + 4194304;         // 2,097,152 f (xc_bf)
  float* proj   = xcbf_f + 2097152;        //   262,144 f
  float* pp     = proj + 262144;           // 1,048,576 f split-K partials
  float* dtb    = pp + 1048576;            // 4,194,304 f
  float* T      = dtb + 4194304;           // 2,097,152 f
  float* E      = T + 2097152;             // 2,097,152 f
  float* hbf_f  = E + 2097152;             // 1,048,576 f (h_bf)
  float* wbf    = hbf_f + 1048576;         //   819,200 f (bf16 weights)

  unsigned short* xzb   = (unsigned short*)xzb_f;
  __hip_bfloat16* xc_bf = (__hip_bfloat16*)xcbf_f;
  __hip_bfloat16* h_bf  = (__hip_bfloat16*)hbf_f;
  __hip_bfloat16* Wb_in = (__hip_bfloat16*)wbf;
  __hip_bfloat16* Wb_xp = Wb_in + 1048576;
  __hip_bfloat16* Wb_out = Wb_xp + 65536;
  __hip_bfloat16* y_bf  = (__hip_bfloat16*)xzb;  // cols 0..1023, lda=2048

  // 0+1. weights -> bf16  ||  LayerNorm -> bf16 h   (one dispatch)
  cvt_ln_kernel<<<1600 + BL / 4, 256, 0, stream>>>(
      W_in, W_xprj, W_out, Wb_in, Wb_xp, Wb_out, x, ln_g, ln_b, h_bf);
  // 2. xz = h @ W_in^T  (M=4096, N=2048, K=512) -> bf16 [MFMA 128x128]
  gemm_mfma_128<false, true><<<dim3(2 * DINNER / 128, BL / 128), 256, 0, stream>>>(
      h_bf, DIM_, Wb_in, DIM_, nullptr, 0, xzb, 2 * DINNER, DIM_);
  // 3+4. FUSED conv+SiLU+proj GEMM: pp slices + xc_bf side output
  gemm_proj_conv<<<dim3(1, BL / 64, 4), 256, 0, stream>>>(
      xzb, Wb_xp, conv_w, conv_b, xc_bf, pp, 262144);
  // 5. fused: reduce pp -> proj + dt = softplus(proj[:, :32] @ W_dt^T + b_dt)
  dt_kernel<<<(BL / 8) * 4, 256, 0, stream>>>(pp, proj, W_dt, b_dt, dtb);
  // 6. chunked scan: 64 chunks of 32
  scan1_kernel<<<B_ * NCHUNK * 64, 256, 0, stream>>>(dtb, xc_bf, proj, A_log, T, E);
  combine_kernel<<<(B_ * DINNER * 16) / 256, 256, 0, stream>>>(T, E);
  scan2_kernel<<<B_ * NCHUNK * 4, 256, 0, stream>>>(dtb, xc_bf, proj, A_log, T, Dp, xzb);
  // 7. out = x + y @ W_out^T (M=4096, N=512, K=1024) [64x64, 512 blocks, res]
  gemm_mfma_64<true><<<dim3(DIM_ / 64, BL / 64, 1), 256, 0, stream>>>(
      y_bf, 2048, Wb_out, DINNER, x, DIM_, out, DIM_, DINNER, 0);
}